// Round 6
// baseline (275.550 us; speedup 1.0000x reference)
//
#include <hip/hip_runtime.h>

#define Bdim 64
#define Tdim 2048
#define Fdim 256
#define TAIL 256      // truncated EMA window: 0.8^256 ~ 1e-25, far below fp32 noise
#define NCH 8
#define CHT 32        // TAIL / NCH

#define NCHUNK 8      // Fdim / 32
#define AFD 3         // A-stream register prefetch depth (chunks)

typedef __bf16 bf16x8 __attribute__((ext_vector_type(8)));
typedef float f32x16 __attribute__((ext_vector_type(16)));
typedef unsigned short u16x8 __attribute__((ext_vector_type(8)));

__device__ __forceinline__ unsigned short bf16_rne(float f) {
  unsigned int u = __float_as_uint(f);
  u += 0x7FFFu + ((u >> 16) & 1u);
  return (unsigned short)(u >> 16);
}

// prep: one launch, three block roles.
//  [0,256):    W fp32 -> Wf bf16 in B-fragment order (R3/R5 verified layout):
//              o=(w*32+c*4+s*2+which)*512+lane*8+e holds bf16(W[k][n]),
//              n=w*64+which*32+(lane&31), k=c*32+(2*s+(lane>>5))*8+e.
//  [256,768):  EMA partial sums over t-chunks (verified since round 0).
//  [768,2816): restage x -> xf bf16 in A-fragment order:
//              m-tile mt (32 rows), frag t=c*2+s (1KB): lane dl=hb*32+row,
//              elems = x[mt*32+row][c*32+s*16+hb*8 .. +8]  (R5's LDS map, sans swizzle).
//              gemm then consumes xf as a perfectly sequential 1KB/instr stream.
__global__ void prep(const float* __restrict__ x, const float* __restrict__ W,
                     unsigned short* __restrict__ Wf, float* __restrict__ part,
                     unsigned short* __restrict__ xf) {
  const int blk = blockIdx.x;
  const int tid = threadIdx.x;
  if (blk < Fdim) {
    int o = blk * 256 + tid;
    int e = o & 7, lane = (o >> 3) & 63, wh = (o >> 9) & 1, s = (o >> 10) & 1;
    int c = (o >> 11) & 7, w = o >> 14;
    int n = w * 64 + wh * 32 + (lane & 31);
    int k = c * 32 + (2 * s + (lane >> 5)) * 8 + e;
    Wf[o] = bf16_rne(W[k * Fdim + n]);
  } else if (blk < Fdim + Bdim * NCH) {
    int j = blk - Fdim;                // 0..511
    int b = j & 63, c = j >> 6;
    int f = tid;
    int t0 = Tdim - TAIL + c * CHT;
    float w = 0.2f * exp2f((float)(Tdim - 1 - t0) * -0.32192809488736235f);
    const float* xp = x + ((size_t)b * Tdim + t0) * Fdim + f;
    float s = 0.f;
#pragma unroll
    for (int q = 0; q < CHT; ++q) {
      s += w * xp[(size_t)q * Fdim];
      w *= 1.25f;
    }
    part[(c * Bdim + b) * Fdim + f] = s;
  } else {
    // restage 64 rows: thread -> row r=tid>>2, col granules g=p*4+(tid&3)
    const int bb = blk - (Fdim + Bdim * NCH);   // 0..2047
    const int r = tid >> 2, q = tid & 3;
    const float* ap = x + ((size_t)bb * 64 + r) * Fdim + q * 8;
    float4 av[8][2];
#pragma unroll
    for (int p = 0; p < 8; ++p) {               // 16 coalesced dwordx4 in flight
      av[p][0] = *(const float4*)(ap + p * 32);
      av[p][1] = *(const float4*)(ap + p * 32 + 4);
    }
    const int mt = bb * 2 + (r >> 5);
    const int rr = r & 31;
#pragma unroll
    for (int p = 0; p < 8; ++p) {
      int g = p * 4 + q, c = g >> 2, s = (g >> 1) & 1, hb = g & 1;
      float4 v0 = av[p][0], v1 = av[p][1];
      u16x8 w;
      w[0] = bf16_rne(v0.x); w[1] = bf16_rne(v0.y);
      w[2] = bf16_rne(v0.z); w[3] = bf16_rne(v0.w);
      w[4] = bf16_rne(v1.x); w[5] = bf16_rne(v1.y);
      w[6] = bf16_rne(v1.z); w[7] = bf16_rne(v1.w);
      *(u16x8*)&xf[((size_t)((mt * 16 + c * 2 + s) * 64 + hb * 32 + rr)) * 8] = w;
    }
  }
}

// out[row][n] = sum_k x[row][k]*W[k][n] + bias[n] + lastref[b][n]
// PURE-STREAM GEMM: no A-LDS, no cvt, no loop barriers.
//  block = 4 waves: wave(mw,nw) owns m-tile blk*2+mw (32 rows) x n-half nw (128 cols).
//  A: sequential 1KB/instr fragment stream from xf (L3-hot), depth-AFD reg prefetch.
//  B: fragment stream from Wf (L2-hot), depth-2 reg prefetch.
//  Fully unrolled -> all prefetch indices static (no scratch), counted vmcnts.
__global__ __launch_bounds__(256, 3)
void gemm_fused(const unsigned short* __restrict__ xf, const unsigned short* __restrict__ Wf,
                const float* __restrict__ bias, const float* __restrict__ part,
                float* __restrict__ out) {
  __shared__ float lref[Fdim];                  // 1 KB total LDS

  const int tid = threadIdx.x;
  const int blk = blockIdx.x;            // 0..2047
  const int b = blk >> 5;                // batch
  const int wave = tid >> 6;
  const int mw = wave >> 1;              // m-tile within block
  const int nw = wave & 1;               // n-half (128 cols)
  const int lane = tid & 63;
  const int lm = lane & 31;
  const int half = lane >> 5;

  {  // lastref[b][n] + bias[n]
    float s = bias[tid];
#pragma unroll
    for (int c = 0; c < NCH; ++c) s += part[(c * Bdim + b) * Fdim + tid];
    lref[tid] = s;
  }
  __syncthreads();                       // the only barrier

  const size_t mt = (size_t)blk * 2 + mw;          // 0..4095
  const unsigned short* ax = xf + mt * (16 * 512) + lane * 8;  // frag t at ax + t*512
  const unsigned short* bx = Wf + lane * 8;

  // B frag (c,s,j): n-subtile j in [0,4), w = nw*2 + (j>>1), which = j&1
#define BOFF(c, s, j) ((size_t)(((nw * 2 + ((j) >> 1)) * 32 + (c) * 4 + (s) * 2 + ((j) & 1))) * 512)

  f32x16 acc[4] = {};                    // 4 n-subtiles of 32x32
  bf16x8 Af[AFD][2];                     // [chunk slot][s]
  bf16x8 Bf[2][2][4];                    // [chunk parity][s][j]

#pragma unroll
  for (int p = 0; p < AFD; ++p)          // A chunks 0..AFD-1 in flight
#pragma unroll
    for (int s = 0; s < 2; ++s)
      Af[p][s] = *(const bf16x8*)(ax + (size_t)(p * 2 + s) * 512);
#pragma unroll
  for (int cc = 0; cc < 2; ++cc)         // B chunks 0,1 in flight
#pragma unroll
    for (int s = 0; s < 2; ++s)
#pragma unroll
      for (int j = 0; j < 4; ++j)
        Bf[cc][s][j] = *(const bf16x8*)(bx + BOFF(cc, s, j));

#pragma unroll
  for (int c = 0; c < NCHUNK; ++c) {
    const int slot = c % AFD;
    const int par = c & 1;
#pragma unroll
    for (int s = 0; s < 2; ++s) {
      bf16x8 a = Af[slot][s];
      acc[0] = __builtin_amdgcn_mfma_f32_32x32x16_bf16(a, Bf[par][s][0], acc[0], 0, 0, 0);
      acc[1] = __builtin_amdgcn_mfma_f32_32x32x16_bf16(a, Bf[par][s][1], acc[1], 0, 0, 0);
      acc[2] = __builtin_amdgcn_mfma_f32_32x32x16_bf16(a, Bf[par][s][2], acc[2], 0, 0, 0);
      acc[3] = __builtin_amdgcn_mfma_f32_32x32x16_bf16(a, Bf[par][s][3], acc[3], 0, 0, 0);
    }
    if (c + AFD < NCHUNK) {              // A refill: AFD-chunk latency gap
#pragma unroll
      for (int s = 0; s < 2; ++s)
        Af[slot][s] = *(const bf16x8*)(ax + (size_t)((c + AFD) * 2 + s) * 512);
    }
    if (c + 2 < NCHUNK) {                // B refill: 2-chunk latency gap
#pragma unroll
      for (int s = 0; s < 2; ++s)
#pragma unroll
        for (int j = 0; j < 4; ++j)
          Bf[par][s][j] = *(const bf16x8*)(bx + BOFF(c + 2, s, j));
    }
  }
#undef BOFF

  // epilogue: C/D layout col=lane&31, row=(r&3)+8*(r>>2)+4*(lane>>5)  [m74/m101]
  float* op = out + mt * 32 * Fdim + nw * 128;
  const int rbase = 4 * half;
#pragma unroll
  for (int j = 0; j < 4; ++j) {
    float lb = lref[nw * 128 + j * 32 + lm];
#pragma unroll
    for (int r = 0; r < 16; ++r) {
      int rowi = (r & 3) + 8 * (r >> 2) + rbase;
      op[(size_t)rowi * Fdim + j * 32 + lm] = acc[j][r] + lb;
    }
  }
}

extern "C" void kernel_launch(void* const* d_in, const int* in_sizes, int n_in,
                              void* d_out, int out_size, void* d_ws, size_t ws_size,
                              hipStream_t stream) {
  const float* x = (const float*)d_in[0];
  const float* W = (const float*)d_in[1];
  const float* bias = (const float*)d_in[2];
  float* out = (float*)d_out;

  unsigned short* Wf = (unsigned short*)d_ws;                                    // 128 KB
  float* part = (float*)((char*)d_ws + 131072);                                  // 512 KB
  unsigned short* xf = (unsigned short*)((char*)d_ws + 131072 + 524288);         // 64 MB

  prep<<<Fdim + Bdim * NCH + 2048, 256, 0, stream>>>(x, W, Wf, part, xf);
  gemm_fused<<<(Bdim * Tdim) / 64, 256, 0, stream>>>(xf, Wf, bias, part, out);
}

// Round 7
// 256.758 us; speedup vs baseline: 1.0732x; 1.0732x over previous
//
#include <hip/hip_runtime.h>

#define Bdim 64
#define Tdim 2048
#define Fdim 256
#define TAIL 256      // truncated EMA window: 0.8^256 ~ 1e-25, far below fp32 noise
#define NCH 8
#define CHT 32        // TAIL / NCH

#define NCHUNK 8      // Fdim / 32

typedef __bf16 bf16x8 __attribute__((ext_vector_type(8)));
typedef float f32x16 __attribute__((ext_vector_type(16)));
typedef unsigned short u16x4 __attribute__((ext_vector_type(4)));
typedef unsigned short u16x8 __attribute__((ext_vector_type(8)));

__device__ __forceinline__ unsigned short bf16_rne(float f) {
  unsigned int u = __float_as_uint(f);
  u += 0x7FFFu + ((u >> 16) & 1u);
  return (unsigned short)(u >> 16);
}

// prep (verified since R3/R5):
//  blocks [0,256):  W fp32 -> Wf bf16 in B-fragment order:
//    o=(w*32+c*4+s*2+which)*512+lane*8+e holds bf16(W[k][n]),
//    n=w*64+which*32+(lane&31), k=c*32+(2*s+(lane>>5))*8+e.
//  blocks [256,768): EMA partial sums over t-chunks.
__global__ void prep(const float* __restrict__ x, const float* __restrict__ W,
                     unsigned short* __restrict__ Wf, float* __restrict__ part) {
  const int blk = blockIdx.x;
  const int tid = threadIdx.x;
  if (blk < Fdim) {
    int o = blk * 256 + tid;
    int e = o & 7, lane = (o >> 3) & 63, wh = (o >> 9) & 1, s = (o >> 10) & 1;
    int c = (o >> 11) & 7, w = o >> 14;
    int n = w * 64 + wh * 32 + (lane & 31);
    int k = c * 32 + (2 * s + (lane >> 5)) * 8 + e;
    Wf[o] = bf16_rne(W[k * Fdim + n]);
  } else {
    int j = blk - Fdim;                // 0..511
    int b = j & 63, c = j >> 6;
    int f = tid;
    int t0 = Tdim - TAIL + c * CHT;
    float w = 0.2f * exp2f((float)(Tdim - 1 - t0) * -0.32192809488736235f);
    const float* xp = x + ((size_t)b * Tdim + t0) * Fdim + f;
    float s = 0.f;
#pragma unroll
    for (int q = 0; q < CHT; ++q) {
      s += w * xp[(size_t)q * Fdim];
      w *= 1.25f;
    }
    part[(c * Bdim + b) * Fdim + f] = s;
  }
}

// out[row][n] = sum_k x[row][k]*W[k][n] + bias[n] + lastref[b][n]
// ZERO-BARRIER continuous-stream GEMM. Block = 4 independent waves:
// wave (mw=w>>1, nw=w&1) owns m-tile mt=blk*2+mw (32 rows) x n-half nw (128 cols).
// Per chunk c (fully unrolled):
//   issue 4 coalesced A dwordx4 loads (chunk c+2)   -> continuous HBM read stream
//   cvt + 4 ds_write_b64 (chunk c+1) into wave-PRIVATE LDS (no __syncthreads!)
//   2 ds_read_b128 A-fragments (chunk c)
//   8 MFMA; B frags refilled-after-use from fragment-ordered Wf (L2-hot)
// lref computed per-lane in registers (no LDS, no barrier).
// LDS frag stride 1040B => ds_write_b64 and ds_read_b128 both <=2-way (free).
__global__ __launch_bounds__(256, 3)
void gemm_fused(const float* __restrict__ x, const unsigned short* __restrict__ Wf,
                const float* __restrict__ bias, const float* __restrict__ part,
                float* __restrict__ out) {
  __shared__ unsigned short At[4][2][2][520];   // [wave][buf][s][dl*8+hb2*4+e] = 16640 B

  const int tid = threadIdx.x;
  const int blk = blockIdx.x;            // 0..2047
  const int b = blk >> 5;                // batch
  const int wave = tid >> 6;
  const int mw = wave >> 1;
  const int nw = wave & 1;
  const int lane = tid & 63;
  const int lm = lane & 31;
  const int half = lane >> 5;
  const size_t mt = (size_t)blk * 2 + mw;

  // per-lane lastref+bias for the 4 n-subtiles this lane stores
  float lref[4];
#pragma unroll
  for (int j = 0; j < 4; ++j) {
    int n = nw * 128 + j * 32 + lm;
    float s = bias[n];
#pragma unroll
    for (int c = 0; c < NCH; ++c) s += part[(c * Bdim + b) * Fdim + n];
    lref[j] = s;
  }

  // A load map: lane -> row arow=lane>>3, 16B col piece acol=(lane&7)*4 floats.
  // instr p covers rows p*8+arow: 8 lanes x 16B = full 128B line per row.
  const int arow = lane >> 3;
  const int acol = (lane & 7) * 4;
  const float* ax = x + (mt * 32 + arow) * Fdim + acol;
  // dest: granule G=(lane&7)>>1 = 2s+hb; s=G>>1, hb=G&1, hb2=lane&1; dl=hb*32+p*8+arow
  const int ds_ = ((lane & 7) >> 2);
  const int dhb = ((lane & 7) >> 1) & 1;
  const int dh2 = lane & 1;

  // B fragment stream (frag (c,s,sub): w_old=nw*2+(sub>>1), which=sub&1)
  const unsigned short* bx = Wf + lane * 8;
#define BOFF(c, s, sub) \
  ((size_t)(((nw * 2 + ((sub) >> 1)) * 32 + (c) * 4 + (s) * 2 + ((sub) & 1))) * 512)

  f32x16 acc[4] = {};          // 4 n-subtiles of 32x32
  float4 Ar[2][4];             // raw A fp32, [chunk&1][p]
  bf16x8 Bf[2][4];             // current chunk's B frags [s][sub]

#define ALOAD(k, slot)                                             \
  {                                                                \
    const float* s4 = ax + (k) * 32;                               \
    Ar[slot][0] = *(const float4*)(s4);                            \
    Ar[slot][1] = *(const float4*)(s4 + 8 * Fdim);                 \
    Ar[slot][2] = *(const float4*)(s4 + 16 * Fdim);                \
    Ar[slot][3] = *(const float4*)(s4 + 24 * Fdim);                \
  }
#define ACVT(slot, buf)                                            \
  {                                                                \
    _Pragma("unroll") for (int p = 0; p < 4; ++p) {                \
      float4 v = Ar[slot][p];                                      \
      u16x4 wv;                                                    \
      wv[0] = bf16_rne(v.x); wv[1] = bf16_rne(v.y);                \
      wv[2] = bf16_rne(v.z); wv[3] = bf16_rne(v.w);                \
      int dl = dhb * 32 + p * 8 + arow;                            \
      *(u16x4*)&At[wave][buf][ds_][dl * 8 + dh2 * 4] = wv;         \
    }                                                              \
  }

  // ---- prologue ----
  ALOAD(0, 0);
  ALOAD(1, 1);
#pragma unroll
  for (int s = 0; s < 2; ++s)
#pragma unroll
    for (int sub = 0; sub < 4; ++sub)
      Bf[s][sub] = *(const bf16x8*)(bx + BOFF(0, s, sub));
  ACVT(0, 0);                       // stage chunk 0 into buf 0

  // ---- main loop: zero barriers ----
#pragma unroll
  for (int c = 0; c < NCHUNK; ++c) {
    const int cur = c & 1, nxt = cur ^ 1;
    if (c + 2 < NCHUNK) ALOAD(c + 2, cur);            // refill freed raw slot
    // A fragments of chunk c (written last iter / prologue)
    bf16x8 a0 = *(const bf16x8*)&At[wave][cur][0][lane * 8];
    bf16x8 a1 = *(const bf16x8*)&At[wave][cur][1][lane * 8];
    if (c + 1 < NCHUNK) ACVT(nxt, nxt);               // stage chunk c+1 into other buf
#pragma unroll
    for (int s = 0; s < 2; ++s) {
      bf16x8 a = (s == 0) ? a0 : a1;
      acc[0] = __builtin_amdgcn_mfma_f32_32x32x16_bf16(a, Bf[s][0], acc[0], 0, 0, 0);
      acc[1] = __builtin_amdgcn_mfma_f32_32x32x16_bf16(a, Bf[s][1], acc[1], 0, 0, 0);
      acc[2] = __builtin_amdgcn_mfma_f32_32x32x16_bf16(a, Bf[s][2], acc[2], 0, 0, 0);
      acc[3] = __builtin_amdgcn_mfma_f32_32x32x16_bf16(a, Bf[s][3], acc[3], 0, 0, 0);
      if (c + 1 < NCHUNK) {        // refill B frags with chunk c+1 (after use)
#pragma unroll
        for (int sub = 0; sub < 4; ++sub)
          Bf[s][sub] = *(const bf16x8*)(bx + BOFF(c + 1, s, sub));
      }
    }
  }
#undef BOFF
#undef ALOAD
#undef ACVT

  // epilogue: C/D layout col=lane&31, row=(r&3)+8*(r>>2)+4*(lane>>5)  [m74/m101]
  float* op = out + mt * 32 * Fdim + nw * 128;
  const int rbase = 4 * half;
#pragma unroll
  for (int j = 0; j < 4; ++j) {
    float lb = lref[j];
#pragma unroll
    for (int r = 0; r < 16; ++r) {
      int rowi = (r & 3) + 8 * (r >> 2) + rbase;
      op[(size_t)rowi * Fdim + j * 32 + lm] = acc[j][r] + lb;
    }
  }
}

extern "C" void kernel_launch(void* const* d_in, const int* in_sizes, int n_in,
                              void* d_out, int out_size, void* d_ws, size_t ws_size,
                              hipStream_t stream) {
  const float* x = (const float*)d_in[0];
  const float* W = (const float*)d_in[1];
  const float* bias = (const float*)d_in[2];
  float* out = (float*)d_out;

  unsigned short* Wf = (unsigned short*)d_ws;                      // 128 KB
  float* part = (float*)((char*)d_ws + 131072);                    // 512 KB

  prep<<<Fdim + Bdim * NCH, 256, 0, stream>>>(x, W, Wf, part);
  gemm_fused<<<(Bdim * Tdim) / 64, 256, 0, stream>>>(x, Wf, bias, part, out);
}